// Round 1
// baseline (1575.802 us; speedup 1.0000x reference)
//
#include <hip/hip_runtime.h>
#include <hip/hip_bf16.h>

#define N_ENT    100000
#define NUM_REL  400
#define DIM      128
#define NUM_EDGES 800000
#define E_HALF   400000

// ---------------- deg histogram ----------------
__global__ __launch_bounds__(256) void deg_kernel(const int* __restrict__ rows,
                                                  float* __restrict__ deg_in,
                                                  float* __restrict__ deg_out) {
    int e = blockIdx.x * 256 + threadIdx.x;
    if (e >= NUM_EDGES) return;
    int row = rows[e];
    float* deg = (e < E_HALF) ? deg_in : deg_out;
    unsafeAtomicAdd(deg + row, 1.0f);
}

// ---------------- deg -> dinv (in place) ----------------
__global__ __launch_bounds__(256) void dinv_kernel(float* __restrict__ a, float* __restrict__ b) {
    int i = blockIdx.x * 256 + threadIdx.x;
    if (i >= N_ENT) return;
    float d = a[i];
    a[i] = (d > 0.0f) ? rsqrtf(d) : 0.0f;
    d = b[i];
    b[i] = (d > 0.0f) ? rsqrtf(d) : 0.0f;
}

// ---------------- edge aggregation (32 lanes per edge) ----------------
__global__ __launch_bounds__(256) void edge_agg_kernel(
    const int* __restrict__ rows, const int* __restrict__ cols, const int* __restrict__ etype,
    const float4* __restrict__ x4, const float4* __restrict__ r4,
    const float* __restrict__ dinv_in, const float* __restrict__ dinv_out,
    float* __restrict__ agg_in, float* __restrict__ agg_out) {
    int gid = blockIdx.x * 256 + threadIdx.x;
    int e = gid >> 5;
    if (e >= NUM_EDGES) return;
    int c = gid & 31;
    int row = rows[e];
    int col = cols[e];
    int t = etype[e];
    bool isIn = (e < E_HALF);
    const float* dinv = isIn ? dinv_in : dinv_out;
    float norm = dinv[row] * dinv[col];
    if (norm == 0.0f) return;
    float4 xj = x4[col * 32 + c];
    float4 hr = r4[t * 32 + c];
    float* agg = (isIn ? agg_in : agg_out) + row * DIM + c * 4;
    unsafeAtomicAdd(agg + 0, norm * (xj.x - hr.x));
    unsafeAtomicAdd(agg + 1, norm * (xj.y - hr.y));
    unsafeAtomicAdd(agg + 2, norm * (xj.z - hr.z));
    unsafeAtomicAdd(agg + 3, norm * (xj.w - hr.w));
}

// ---------------- fused GEMM: out = tanh(([agg_in|agg_out|x-loop] @ [w_in;w_out;w_loop])/3 + bias)
// M=100000, N=128, K=384.  128x128 tile per block, 256 threads, 8x8 per-thread.
__global__ __launch_bounds__(256) void fused_gemm_kernel(
    const float* __restrict__ agg_in, const float* __restrict__ agg_out,
    const float* __restrict__ x, const float* __restrict__ loop_rel,
    const float* __restrict__ w_in, const float* __restrict__ w_out, const float* __restrict__ w_loop,
    const float* __restrict__ bias, float* __restrict__ out) {
    __shared__ float As[16][128];   // A transposed: As[k][row]
    __shared__ float Ws[16][128];   // Ws[k][col]

    int tid = threadIdx.x;
    int row0 = blockIdx.x * 128;
    int rg = tid >> 4;   // 0..15 row group (8 rows each)
    int cg = tid & 15;   // 0..15 col group (8 cols each)

    float acc[8][8] = {};

    const float* Asrc[3] = {agg_in, agg_out, x};
    const float* Wsrc[3] = {w_in, w_out, w_loop};

    for (int kc = 0; kc < 24; ++kc) {
        int s = kc >> 3;            // 0: in, 1: out, 2: loop
        int k0 = (kc & 7) * 16;     // 0..112 within source
        const float* A = Asrc[s];
        const float* W = Wsrc[s];

        // stage A tile transposed: 128 rows x 16 k
        #pragma unroll
        for (int p = 0; p < 2; ++p) {
            int idx = tid + p * 256;       // 0..511
            int r = idx >> 2;              // 0..127
            int q = idx & 3;               // 0..3 (quad of k)
            int grow = row0 + r;
            int gr = grow < N_ENT ? grow : (N_ENT - 1);
            float4 v = *(const float4*)&A[gr * DIM + k0 + q * 4];
            if (s == 2) {
                float4 lr = *(const float4*)&loop_rel[k0 + q * 4];
                v.x -= lr.x; v.y -= lr.y; v.z -= lr.z; v.w -= lr.w;
            }
            As[q * 4 + 0][r] = v.x;
            As[q * 4 + 1][r] = v.y;
            As[q * 4 + 2][r] = v.z;
            As[q * 4 + 3][r] = v.w;
        }
        // stage W tile: 16 k x 128 cols
        #pragma unroll
        for (int p = 0; p < 2; ++p) {
            int idx = tid + p * 256;       // 0..511
            int r = idx >> 5;              // 0..15 (k)
            int q = idx & 31;              // col quad
            float4 v = *(const float4*)&W[(k0 + r) * DIM + q * 4];
            *(float4*)&Ws[r][q * 4] = v;
        }
        __syncthreads();

        #pragma unroll
        for (int kk = 0; kk < 16; ++kk) {
            float4 a0 = *(const float4*)&As[kk][rg * 8];
            float4 a1 = *(const float4*)&As[kk][rg * 8 + 4];
            float4 b0 = *(const float4*)&Ws[kk][cg * 8];
            float4 b1 = *(const float4*)&Ws[kk][cg * 8 + 4];
            float a[8] = {a0.x, a0.y, a0.z, a0.w, a1.x, a1.y, a1.z, a1.w};
            float b[8] = {b0.x, b0.y, b0.z, b0.w, b1.x, b1.y, b1.z, b1.w};
            #pragma unroll
            for (int i = 0; i < 8; ++i)
                #pragma unroll
                for (int j = 0; j < 8; ++j)
                    acc[i][j] += a[i] * b[j];
        }
        __syncthreads();
    }

    // epilogue: tanh(acc/3 + bias)
    float bb[8];
    *(float4*)&bb[0] = *(const float4*)&bias[cg * 8];
    *(float4*)&bb[4] = *(const float4*)&bias[cg * 8 + 4];
    const float third = 1.0f / 3.0f;
    #pragma unroll
    for (int i = 0; i < 8; ++i) {
        int grow = row0 + rg * 8 + i;
        if (grow < N_ENT) {
            float o[8];
            #pragma unroll
            for (int j = 0; j < 8; ++j)
                o[j] = tanhf(acc[i][j] * third + bb[j]);
            *(float4*)&out[grow * DIM + cg * 8] = *(float4*)&o[0];
            *(float4*)&out[grow * DIM + cg * 8 + 4] = *(float4*)&o[4];
        }
    }
}

// ---------------- r_out = r @ w_rel  (400x128 @ 128x128) ----------------
__global__ __launch_bounds__(128) void rel_gemm_kernel(const float* __restrict__ r,
                                                       const float* __restrict__ w_rel,
                                                       float* __restrict__ r_out) {
    __shared__ float rrow[128];
    int i = blockIdx.x;
    int j = threadIdx.x;
    rrow[j] = r[i * DIM + j];
    __syncthreads();
    float acc = 0.0f;
    #pragma unroll 8
    for (int k = 0; k < DIM; ++k)
        acc += rrow[k] * w_rel[k * DIM + j];
    r_out[i * DIM + j] = acc;
}

extern "C" void kernel_launch(void* const* d_in, const int* in_sizes, int n_in,
                              void* d_out, int out_size, void* d_ws, size_t ws_size,
                              hipStream_t stream) {
    const float* x        = (const float*)d_in[0];
    const float* r        = (const float*)d_in[1];
    const int*   ei       = (const int*)d_in[2];   // [2][800000]: rows then cols
    const int*   et       = (const int*)d_in[3];
    const float* w_in     = (const float*)d_in[4];
    const float* w_out    = (const float*)d_in[5];
    const float* w_loop   = (const float*)d_in[6];
    const float* w_rel    = (const float*)d_in[7];
    const float* loop_rel = (const float*)d_in[8];
    const float* bias     = (const float*)d_in[9];

    float* out   = (float*)d_out;            // 100000*128
    float* r_out = out + (size_t)N_ENT * DIM;

    float* ws      = (float*)d_ws;
    float* agg_in  = ws;                                  // 12.8M
    float* agg_out = ws + (size_t)N_ENT * DIM;            // 12.8M
    float* deg_in  = ws + 2ull * N_ENT * DIM;             // 100k (-> dinv)
    float* deg_out = deg_in + N_ENT;                      // 100k (-> dinv)

    size_t zero_floats = 2ull * N_ENT * DIM + 2ull * N_ENT;
    hipMemsetAsync(ws, 0, zero_floats * sizeof(float), stream);

    const int* rows = ei;
    const int* cols = ei + NUM_EDGES;

    deg_kernel<<<(NUM_EDGES + 255) / 256, 256, 0, stream>>>(rows, deg_in, deg_out);
    dinv_kernel<<<(N_ENT + 255) / 256, 256, 0, stream>>>(deg_in, deg_out);

    int edge_threads = NUM_EDGES * 32;
    edge_agg_kernel<<<(edge_threads + 255) / 256, 256, 0, stream>>>(
        rows, cols, et, (const float4*)x, (const float4*)r,
        deg_in, deg_out, agg_in, agg_out);

    fused_gemm_kernel<<<(N_ENT + 127) / 128, 256, 0, stream>>>(
        agg_in, agg_out, x, loop_rel, w_in, w_out, w_loop, bias, out);

    rel_gemm_kernel<<<NUM_REL, 128, 0, stream>>>(r, w_rel, r_out);
}

// Round 2
// 557.022 us; speedup vs baseline: 2.8290x; 2.8290x over previous
//
#include <hip/hip_runtime.h>
#include <hip/hip_bf16.h>

#define N_ENT    100000
#define NUM_REL  400
#define DIM      128
#define NUM_EDGES 800000
#define E_HALF   400000

// ---------------- deg histogram (int atomics, both halves) ----------------
__global__ __launch_bounds__(256) void deg_kernel(const int* __restrict__ rows,
                                                  int* __restrict__ deg) {
    int e = blockIdx.x * 256 + threadIdx.x;
    if (e >= NUM_EDGES) return;
    int half = (e >= E_HALF) ? 1 : 0;
    atomicAdd(&deg[half * N_ENT + rows[e]], 1);
}

// ---------------- deg -> dinv ----------------
__global__ __launch_bounds__(256) void dinv_kernel(const int* __restrict__ deg,
                                                   float* __restrict__ dinv) {
    int i = blockIdx.x * 256 + threadIdx.x;
    if (i >= 2 * N_ENT) return;
    int d = deg[i];
    dinv[i] = (d > 0) ? rsqrtf((float)d) : 0.0f;
}

// ---------------- exclusive scan over deg[0..2N) -> offs ----------------
__global__ __launch_bounds__(1024) void scan_kernel(const int* __restrict__ deg,
                                                    int* __restrict__ offs) {
    __shared__ int sums[1024];
    const int TOT = 2 * N_ENT;
    const int CHUNK = 8192;             // 8 elems per thread
    int tid = threadIdx.x;
    int carry = 0;
    for (int base = 0; base < TOT; base += CHUNK) {
        int idx = base + tid * 8;
        int v[8];
        int s = 0;
        #pragma unroll
        for (int k = 0; k < 8; ++k) {
            int d = (idx + k < TOT) ? deg[idx + k] : 0;
            v[k] = s;
            s += d;
        }
        sums[tid] = s;
        __syncthreads();
        // Hillis-Steele inclusive scan
        for (int off = 1; off < 1024; off <<= 1) {
            int t = (tid >= off) ? sums[tid - off] : 0;
            __syncthreads();
            sums[tid] += t;
            __syncthreads();
        }
        int excl = (tid == 0) ? 0 : sums[tid - 1];
        int tot = sums[1023];
        #pragma unroll
        for (int k = 0; k < 8; ++k)
            if (idx + k < TOT) offs[idx + k] = carry + excl + v[k];
        carry += tot;
        __syncthreads();
    }
}

// ---------------- fill CSR records {col, etype, norm} ----------------
__global__ __launch_bounds__(256) void fill_kernel(const int* __restrict__ rows,
                                                   const int* __restrict__ cols,
                                                   const int* __restrict__ et,
                                                   const float* __restrict__ dinv,
                                                   const int* __restrict__ offs,
                                                   int* __restrict__ cursor,
                                                   int4* __restrict__ recs) {
    int e = blockIdx.x * 256 + threadIdx.x;
    if (e >= NUM_EDGES) return;
    int half = (e >= E_HALF) ? 1 : 0;
    int g = half * N_ENT + rows[e];
    int col = cols[e];
    int t = et[e];
    int pos = atomicAdd(&cursor[g], 1);
    float norm = dinv[g] * dinv[half * N_ENT + col];
    recs[offs[g] + pos] = make_int4(col, t, __float_as_int(norm), 0);
}

// ---------------- gather-aggregate: 32 lanes per (row,half) ----------------
__global__ __launch_bounds__(256) void gather_agg_kernel(const int* __restrict__ offs,
                                                         const int4* __restrict__ recs,
                                                         const float4* __restrict__ x4,
                                                         const float4* __restrict__ r4,
                                                         float* __restrict__ agg_in,
                                                         float* __restrict__ agg_out) {
    int gid = blockIdx.x * 256 + threadIdx.x;
    int g = gid >> 5;
    if (g >= 2 * N_ENT) return;
    int c = gid & 31;
    int start = offs[g];
    int end = (g == 2 * N_ENT - 1) ? NUM_EDGES : offs[g + 1];
    float4 acc = {0.0f, 0.0f, 0.0f, 0.0f};
    for (int e = start; e < end; ++e) {
        int4 rec = recs[e];                   // broadcast across the 32 lanes
        float norm = __int_as_float(rec.z);
        float4 xj = x4[rec.x * 32 + c];
        float4 hr = r4[rec.y * 32 + c];
        acc.x += norm * (xj.x - hr.x);
        acc.y += norm * (xj.y - hr.y);
        acc.z += norm * (xj.z - hr.z);
        acc.w += norm * (xj.w - hr.w);
    }
    int half = (g >= N_ENT) ? 1 : 0;
    int row = g - half * N_ENT;
    float* agg = (half ? agg_out : agg_in) + row * DIM + c * 4;
    *(float4*)agg = acc;
}

// ---------------- fused GEMM: out = tanh(([agg_in|agg_out|x-loop] @ [w_in;w_out;w_loop])/3 + bias)
// M=100000, N=128, K=384.  128x128 tile per block, 256 threads, 8x8 per-thread.
__global__ __launch_bounds__(256) void fused_gemm_kernel(
    const float* __restrict__ agg_in, const float* __restrict__ agg_out,
    const float* __restrict__ x, const float* __restrict__ loop_rel,
    const float* __restrict__ w_in, const float* __restrict__ w_out, const float* __restrict__ w_loop,
    const float* __restrict__ bias, float* __restrict__ out) {
    __shared__ float As[16][128];   // A transposed: As[k][row]
    __shared__ float Ws[16][128];   // Ws[k][col]

    int tid = threadIdx.x;
    int row0 = blockIdx.x * 128;
    int rg = tid >> 4;   // 0..15 row group (8 rows each)
    int cg = tid & 15;   // 0..15 col group (8 cols each)

    float acc[8][8] = {};

    const float* Asrc[3] = {agg_in, agg_out, x};
    const float* Wsrc[3] = {w_in, w_out, w_loop};

    for (int kc = 0; kc < 24; ++kc) {
        int s = kc >> 3;            // 0: in, 1: out, 2: loop
        int k0 = (kc & 7) * 16;     // 0..112 within source
        const float* A = Asrc[s];
        const float* W = Wsrc[s];

        #pragma unroll
        for (int p = 0; p < 2; ++p) {
            int idx = tid + p * 256;       // 0..511
            int r = idx >> 2;              // 0..127
            int q = idx & 3;               // 0..3 (quad of k)
            int grow = row0 + r;
            int gr = grow < N_ENT ? grow : (N_ENT - 1);
            float4 v = *(const float4*)&A[gr * DIM + k0 + q * 4];
            if (s == 2) {
                float4 lr = *(const float4*)&loop_rel[k0 + q * 4];
                v.x -= lr.x; v.y -= lr.y; v.z -= lr.z; v.w -= lr.w;
            }
            As[q * 4 + 0][r] = v.x;
            As[q * 4 + 1][r] = v.y;
            As[q * 4 + 2][r] = v.z;
            As[q * 4 + 3][r] = v.w;
        }
        #pragma unroll
        for (int p = 0; p < 2; ++p) {
            int idx = tid + p * 256;       // 0..511
            int r = idx >> 5;              // 0..15 (k)
            int q = idx & 31;              // col quad
            float4 v = *(const float4*)&W[(k0 + r) * DIM + q * 4];
            *(float4*)&Ws[r][q * 4] = v;
        }
        __syncthreads();

        #pragma unroll
        for (int kk = 0; kk < 16; ++kk) {
            float4 a0 = *(const float4*)&As[kk][rg * 8];
            float4 a1 = *(const float4*)&As[kk][rg * 8 + 4];
            float4 b0 = *(const float4*)&Ws[kk][cg * 8];
            float4 b1 = *(const float4*)&Ws[kk][cg * 8 + 4];
            float a[8] = {a0.x, a0.y, a0.z, a0.w, a1.x, a1.y, a1.z, a1.w};
            float b[8] = {b0.x, b0.y, b0.z, b0.w, b1.x, b1.y, b1.z, b1.w};
            #pragma unroll
            for (int i = 0; i < 8; ++i)
                #pragma unroll
                for (int j = 0; j < 8; ++j)
                    acc[i][j] += a[i] * b[j];
        }
        __syncthreads();
    }

    float bb[8];
    *(float4*)&bb[0] = *(const float4*)&bias[cg * 8];
    *(float4*)&bb[4] = *(const float4*)&bias[cg * 8 + 4];
    const float third = 1.0f / 3.0f;
    #pragma unroll
    for (int i = 0; i < 8; ++i) {
        int grow = row0 + rg * 8 + i;
        if (grow < N_ENT) {
            float o[8];
            #pragma unroll
            for (int j = 0; j < 8; ++j)
                o[j] = tanhf(acc[i][j] * third + bb[j]);
            *(float4*)&out[grow * DIM + cg * 8] = *(float4*)&o[0];
            *(float4*)&out[grow * DIM + cg * 8 + 4] = *(float4*)&o[4];
        }
    }
}

// ---------------- r_out = r @ w_rel  (400x128 @ 128x128) ----------------
__global__ __launch_bounds__(128) void rel_gemm_kernel(const float* __restrict__ r,
                                                       const float* __restrict__ w_rel,
                                                       float* __restrict__ r_out) {
    __shared__ float rrow[128];
    int i = blockIdx.x;
    int j = threadIdx.x;
    rrow[j] = r[i * DIM + j];
    __syncthreads();
    float acc = 0.0f;
    #pragma unroll 8
    for (int k = 0; k < DIM; ++k)
        acc += rrow[k] * w_rel[k * DIM + j];
    r_out[i * DIM + j] = acc;
}

extern "C" void kernel_launch(void* const* d_in, const int* in_sizes, int n_in,
                              void* d_out, int out_size, void* d_ws, size_t ws_size,
                              hipStream_t stream) {
    const float* x        = (const float*)d_in[0];
    const float* r        = (const float*)d_in[1];
    const int*   ei       = (const int*)d_in[2];   // [2][800000]: rows then cols
    const int*   et       = (const int*)d_in[3];
    const float* w_in     = (const float*)d_in[4];
    const float* w_out    = (const float*)d_in[5];
    const float* w_loop   = (const float*)d_in[6];
    const float* w_rel    = (const float*)d_in[7];
    const float* loop_rel = (const float*)d_in[8];
    const float* bias     = (const float*)d_in[9];

    float* out   = (float*)d_out;            // 100000*128
    float* r_out = out + (size_t)N_ENT * DIM;

    // workspace layout
    float* ws      = (float*)d_ws;
    float* agg_in  = ws;                                    // 12.8M f32
    float* agg_out = agg_in + (size_t)N_ENT * DIM;          // 12.8M f32
    int*   deg     = (int*)(agg_out + (size_t)N_ENT * DIM); // 2N int
    int*   cursor  = deg + 2 * N_ENT;                       // 2N int
    int*   offs    = cursor + 2 * N_ENT;                    // 2N int
    float* dinv    = (float*)(offs + 2 * N_ENT);            // 2N f32
    int4*  recs    = (int4*)(dinv + 2 * N_ENT);             // 800k int4 (12.8 MB)

    const int* rows = ei;
    const int* cols = ei + NUM_EDGES;

    // zero deg + cursor (contiguous)
    hipMemsetAsync(deg, 0, 4ull * N_ENT * sizeof(int), stream);

    deg_kernel<<<(NUM_EDGES + 255) / 256, 256, 0, stream>>>(rows, deg);
    dinv_kernel<<<(2 * N_ENT + 255) / 256, 256, 0, stream>>>(deg, dinv);
    scan_kernel<<<1, 1024, 0, stream>>>(deg, offs);
    fill_kernel<<<(NUM_EDGES + 255) / 256, 256, 0, stream>>>(rows, cols, et, dinv, offs, cursor, recs);

    int gather_threads = 2 * N_ENT * 32;
    gather_agg_kernel<<<(gather_threads + 255) / 256, 256, 0, stream>>>(
        offs, recs, (const float4*)x, (const float4*)r, agg_in, agg_out);

    fused_gemm_kernel<<<(N_ENT + 127) / 128, 256, 0, stream>>>(
        agg_in, agg_out, x, loop_rel, w_in, w_out, w_loop, bias, out);

    rel_gemm_kernel<<<NUM_REL, 128, 0, stream>>>(r, w_rel, r_out);
}

// Round 3
// 293.132 us; speedup vs baseline: 5.3757x; 1.9002x over previous
//
#include <hip/hip_runtime.h>
#include <hip/hip_bf16.h>

#define N_ENT    100000
#define NUM_REL  400
#define DIM      128
#define NUM_EDGES 800000
#define E_HALF   400000

using short8 = __attribute__((ext_vector_type(8))) short;
using f32x4  = __attribute__((ext_vector_type(4))) float;

__device__ inline float bf_lo(unsigned u) { return __uint_as_float(u << 16); }
__device__ inline float bf_hi(unsigned u) { return __uint_as_float(u & 0xffff0000u); }
__device__ inline unsigned short f2bf(float f) {
    unsigned u = __float_as_uint(f);
    u = u + 0x7fffu + ((u >> 16) & 1u);   // round-to-nearest-even
    return (unsigned short)(u >> 16);
}

// ---------------- deg histogram ----------------
__global__ __launch_bounds__(256) void deg_kernel(const int* __restrict__ rows,
                                                  int* __restrict__ deg) {
    int e = blockIdx.x * 256 + threadIdx.x;
    if (e >= NUM_EDGES) return;
    int half = (e >= E_HALF) ? 1 : 0;
    atomicAdd(&deg[half * N_ENT + rows[e]], 1);
}

// ---------------- deg -> dinv ----------------
__global__ __launch_bounds__(256) void dinv_kernel(const int* __restrict__ deg,
                                                   float* __restrict__ dinv) {
    int i = blockIdx.x * 256 + threadIdx.x;
    if (i >= 2 * N_ENT) return;
    int d = deg[i];
    dinv[i] = (d > 0) ? rsqrtf((float)d) : 0.0f;
}

// ---------------- segment offsets via wave-atomic allocation ----------------
// offs[g] = disjoint contiguous range start; segment g is [offs[g], offs[g]+deg[g])
__global__ __launch_bounds__(256) void offs_kernel(const int* __restrict__ deg,
                                                   int* __restrict__ offs,
                                                   int* __restrict__ counter) {
    int i = blockIdx.x * 256 + threadIdx.x;
    int lane = threadIdx.x & 63;
    int v = (i < 2 * N_ENT) ? deg[i] : 0;
    int pre = v;
    #pragma unroll
    for (int d = 1; d < 64; d <<= 1) {
        int t = __shfl_up(pre, d);
        if (lane >= d) pre += t;
    }
    int total = __shfl(pre, 63);
    int base = 0;
    if (lane == 0) base = atomicAdd(counter, total);
    base = __shfl(base, 0);
    if (i < 2 * N_ENT) offs[i] = base + pre - v;
}

// ---------------- fill CSR records {col|t<<17, norm} ----------------
__global__ __launch_bounds__(256) void fill_kernel(const int* __restrict__ rows,
                                                   const int* __restrict__ cols,
                                                   const int* __restrict__ et,
                                                   const float* __restrict__ dinv,
                                                   const int* __restrict__ offs,
                                                   int* __restrict__ cursor,
                                                   uint2* __restrict__ recs) {
    int e = blockIdx.x * 256 + threadIdx.x;
    if (e >= NUM_EDGES) return;
    int half = (e >= E_HALF) ? 1 : 0;
    int g = half * N_ENT + rows[e];
    int col = cols[e];
    int t = et[e];
    int pos = atomicAdd(&cursor[g], 1);
    float norm = dinv[g] * dinv[half * N_ENT + col];
    recs[offs[g] + pos] = make_uint2((unsigned)col | ((unsigned)t << 17),
                                     __float_as_uint(norm));
}

// ---------------- prep: xl = bf16(x - loop_rel) ----------------
__global__ __launch_bounds__(256) void prep_x_kernel(const float4* __restrict__ x4,
                                                     const float4* __restrict__ loop4,
                                                     ushort4* __restrict__ xl4) {
    int i = blockIdx.x * 256 + threadIdx.x;
    if (i >= N_ENT * 32) return;
    float4 v = x4[i];
    float4 lr = loop4[i & 31];
    ushort4 o;
    o.x = f2bf(v.x - lr.x);
    o.y = f2bf(v.y - lr.y);
    o.z = f2bf(v.z - lr.z);
    o.w = f2bf(v.w - lr.w);
    xl4[i] = o;
}

// ---------------- prep: wt[n][384] = bf16 W^T concat ; rp = bf16(r - loop_rel) ----------------
__global__ __launch_bounds__(256) void prep_wr_kernel(const float* __restrict__ w_in,
                                                      const float* __restrict__ w_out,
                                                      const float* __restrict__ w_loop,
                                                      const float* __restrict__ r,
                                                      const float* __restrict__ loop_rel,
                                                      unsigned short* __restrict__ wt,
                                                      unsigned short* __restrict__ rp) {
    int i = blockIdx.x * 256 + threadIdx.x;
    if (i < 128 * 384) {
        int n = i / 384;
        int k = i % 384;
        int s = k >> 7;
        int kk = k & 127;
        const float* W = (s == 0) ? w_in : (s == 1) ? w_out : w_loop;
        wt[i] = f2bf(W[kk * DIM + n]);
    } else {
        int j = i - 128 * 384;
        if (j < NUM_REL * DIM)
            rp[j] = f2bf(r[j] - loop_rel[j & 127]);
    }
}

// ---------------- gather-aggregate: 32 lanes per (row,half), bf16 in/out ----------------
__global__ __launch_bounds__(256) void gather_agg_kernel(const int* __restrict__ offs,
                                                         const int* __restrict__ deg,
                                                         const uint2* __restrict__ recs,
                                                         const unsigned short* __restrict__ xl,
                                                         const unsigned short* __restrict__ rp,
                                                         unsigned short* __restrict__ agg) {
    int gid = blockIdx.x * 256 + threadIdx.x;
    int g = gid >> 5;
    if (g >= 2 * N_ENT) return;
    int c = gid & 31;                    // lane handles 4 bf16 (8 B)
    int start = offs[g];
    int end = start + deg[g];
    float a0 = 0.f, a1 = 0.f, a2 = 0.f, a3 = 0.f;
    for (int e = start; e < end; ++e) {
        uint2 rec = recs[e];
        int col = rec.x & 0x1ffff;
        int t = rec.x >> 17;
        float norm = __int_as_float(rec.y);
        uint2 xv = ((const uint2*)(xl + (size_t)col * DIM))[c];
        uint2 rv = ((const uint2*)(rp + (size_t)t * DIM))[c];
        a0 += norm * (bf_lo(xv.x) - bf_lo(rv.x));
        a1 += norm * (bf_hi(xv.x) - bf_hi(rv.x));
        a2 += norm * (bf_lo(xv.y) - bf_lo(rv.y));
        a3 += norm * (bf_hi(xv.y) - bf_hi(rv.y));
    }
    ushort4 o;
    o.x = f2bf(a0); o.y = f2bf(a1); o.z = f2bf(a2); o.w = f2bf(a3);
    ((ushort4*)(agg + (size_t)g * DIM))[c] = o;
}

// ---------------- MFMA GEMM: out = tanh(([aggA|aggB|xl] @ Wcat)/3 + bias) ----------------
// M=100000 (128/block), N=128, K=384. 4 waves 2x2, 4x4 16x16x32 frags per wave. No LDS.
__global__ __launch_bounds__(256) void mfma_gemm_kernel(const unsigned short* __restrict__ aggA,
                                                        const unsigned short* __restrict__ aggB,
                                                        const unsigned short* __restrict__ xl,
                                                        const unsigned short* __restrict__ wt,
                                                        const float* __restrict__ bias,
                                                        float* __restrict__ out) {
    int tid = threadIdx.x;
    int wave = tid >> 6;
    int lane = tid & 63;
    int wm = wave >> 1, wn = wave & 1;
    int row0 = blockIdx.x * 128 + wm * 64;
    int col0 = wn * 64;
    int lr = lane & 15;
    int lk = (lane >> 4) * 8;

    const unsigned short* Asrc[3] = {aggA, aggB, xl};

    f32x4 acc[4][4];
    #pragma unroll
    for (int mi = 0; mi < 4; ++mi)
        #pragma unroll
        for (int ni = 0; ni < 4; ++ni)
            acc[mi][ni] = (f32x4){0.f, 0.f, 0.f, 0.f};

    #pragma unroll
    for (int s = 0; s < 3; ++s) {
        const unsigned short* A = Asrc[s];
        #pragma unroll
        for (int kk = 0; kk < 4; ++kk) {
            int kA = kk * 32 + lk;          // 0..127 within source
            short8 a[4], b[4];
            #pragma unroll
            for (int mi = 0; mi < 4; ++mi) {
                int rrow = row0 + mi * 16 + lr;
                if (rrow >= N_ENT) rrow = N_ENT - 1;
                a[mi] = *(const short8*)(A + (size_t)rrow * DIM + kA);
            }
            #pragma unroll
            for (int ni = 0; ni < 4; ++ni) {
                int n = col0 + ni * 16 + lr;
                b[ni] = *(const short8*)(wt + n * 384 + s * 128 + kA);
            }
            #pragma unroll
            for (int mi = 0; mi < 4; ++mi)
                #pragma unroll
                for (int ni = 0; ni < 4; ++ni)
                    acc[mi][ni] = __builtin_amdgcn_mfma_f32_16x16x32_bf16(a[mi], b[ni], acc[mi][ni], 0, 0, 0);
        }
    }

    const float third = 1.0f / 3.0f;
    float bb[4];
    #pragma unroll
    for (int ni = 0; ni < 4; ++ni) bb[ni] = bias[col0 + ni * 16 + lr];

    #pragma unroll
    for (int mi = 0; mi < 4; ++mi) {
        #pragma unroll
        for (int reg = 0; reg < 4; ++reg) {
            int grow = row0 + mi * 16 + (lane >> 4) * 4 + reg;
            if (grow < N_ENT) {
                #pragma unroll
                for (int ni = 0; ni < 4; ++ni)
                    out[(size_t)grow * DIM + col0 + ni * 16 + lr] =
                        tanhf(acc[mi][ni][reg] * third + bb[ni]);
            }
        }
    }
}

// ---------------- r_out = r @ w_rel  (400x128 @ 128x128, f32) ----------------
__global__ __launch_bounds__(128) void rel_gemm_kernel(const float* __restrict__ r,
                                                       const float* __restrict__ w_rel,
                                                       float* __restrict__ r_out) {
    __shared__ float rrow[128];
    int i = blockIdx.x;
    int j = threadIdx.x;
    rrow[j] = r[i * DIM + j];
    __syncthreads();
    float acc = 0.0f;
    #pragma unroll 8
    for (int k = 0; k < DIM; ++k)
        acc += rrow[k] * w_rel[k * DIM + j];
    r_out[i * DIM + j] = acc;
}

extern "C" void kernel_launch(void* const* d_in, const int* in_sizes, int n_in,
                              void* d_out, int out_size, void* d_ws, size_t ws_size,
                              hipStream_t stream) {
    const float* x        = (const float*)d_in[0];
    const float* r        = (const float*)d_in[1];
    const int*   ei       = (const int*)d_in[2];   // [2][800000]: rows then cols
    const int*   et       = (const int*)d_in[3];
    const float* w_in     = (const float*)d_in[4];
    const float* w_out    = (const float*)d_in[5];
    const float* w_loop   = (const float*)d_in[6];
    const float* w_rel    = (const float*)d_in[7];
    const float* loop_rel = (const float*)d_in[8];
    const float* bias     = (const float*)d_in[9];

    float* out   = (float*)d_out;            // 100000*128
    float* r_out = out + (size_t)N_ENT * DIM;

    // -------- workspace layout (bytes) --------
    unsigned short* agg = (unsigned short*)d_ws;            // [2N][128] bf16 (in | out)
    unsigned short* xl  = agg + 2ull * N_ENT * DIM;         // [N][128] bf16
    unsigned short* wt  = xl + (size_t)N_ENT * DIM;         // [128][384] bf16
    unsigned short* rp  = wt + 128 * 384;                   // [400][128] bf16
    uint2* recs = (uint2*)(rp + NUM_REL * DIM);             // 800k x 8 B
    int*   deg     = (int*)(recs + NUM_EDGES);              // 2N
    int*   cursor  = deg + 2 * N_ENT;                       // 2N
    int*   counter = cursor + 2 * N_ENT;                    // 1 (+3 pad)
    int*   offs    = counter + 4;                           // 2N
    float* dinv    = (float*)(offs + 2 * N_ENT);            // 2N

    const int* rows = ei;
    const int* cols = ei + NUM_EDGES;

    // zero deg + cursor + counter (contiguous)
    hipMemsetAsync(deg, 0, (4ull * N_ENT + 4) * sizeof(int), stream);

    deg_kernel<<<(NUM_EDGES + 255) / 256, 256, 0, stream>>>(rows, deg);
    dinv_kernel<<<(2 * N_ENT + 255) / 256, 256, 0, stream>>>(deg, dinv);
    offs_kernel<<<(2 * N_ENT + 255) / 256, 256, 0, stream>>>(deg, offs, counter);
    fill_kernel<<<(NUM_EDGES + 255) / 256, 256, 0, stream>>>(rows, cols, et, dinv, offs, cursor, recs);

    prep_x_kernel<<<(N_ENT * 32 + 255) / 256, 256, 0, stream>>>(
        (const float4*)x, (const float4*)loop_rel, (ushort4*)xl);
    prep_wr_kernel<<<(128 * 384 + NUM_REL * DIM + 255) / 256, 256, 0, stream>>>(
        w_in, w_out, w_loop, r, loop_rel, wt, rp);

    gather_agg_kernel<<<(2 * N_ENT * 32 + 255) / 256, 256, 0, stream>>>(
        offs, deg, recs, xl, rp, agg);

    mfma_gemm_kernel<<<(N_ENT + 127) / 128, 256, 0, stream>>>(
        agg, agg + (size_t)N_ENT * DIM, xl, wt, bias, out);

    rel_gemm_kernel<<<NUM_REL, 128, 0, stream>>>(r, w_rel, r_out);
}

// Round 4
// 215.807 us; speedup vs baseline: 7.3019x; 1.3583x over previous
//
#include <hip/hip_runtime.h>
#include <hip/hip_bf16.h>

#define N_ENT    100000
#define NUM_REL  400
#define DIM      128
#define NUM_EDGES 800000
#define E_HALF   400000

using short8 = __attribute__((ext_vector_type(8))) short;
using f32x4  = __attribute__((ext_vector_type(4))) float;

__device__ __forceinline__ float bf_lo(unsigned u) { return __uint_as_float(u << 16); }
__device__ __forceinline__ float bf_hi(unsigned u) { return __uint_as_float(u & 0xffff0000u); }
__device__ __forceinline__ unsigned short f2bf(float f) {
    unsigned u = __float_as_uint(f);
    u = u + 0x7fffu + ((u >> 16) & 1u);   // RNE
    return (unsigned short)(u >> 16);
}
__device__ __forceinline__ unsigned pack2bf(float a, float b) {
    return (unsigned)f2bf(a) | ((unsigned)f2bf(b) << 16);
}

typedef const __attribute__((address_space(1))) void* gas_t;
typedef __attribute__((address_space(3))) void* las_t;
__device__ __forceinline__ void gll16(const void* g, void* l) {
    __builtin_amdgcn_global_load_lds((gas_t)g, (las_t)l, 16, 0, 0);
}

// ---------------- deg histogram ----------------
__global__ __launch_bounds__(256) void deg_kernel(const int* __restrict__ rows,
                                                  int* __restrict__ deg) {
    int e = blockIdx.x * 256 + threadIdx.x;
    if (e >= NUM_EDGES) return;
    int half = (e >= E_HALF) ? 1 : 0;
    atomicAdd(&deg[half * N_ENT + rows[e]], 1);
}

// ---------------- deg -> dinv ----------------
__global__ __launch_bounds__(256) void dinv_kernel(const int* __restrict__ deg,
                                                   float* __restrict__ dinv) {
    int i = blockIdx.x * 256 + threadIdx.x;
    if (i >= 2 * N_ENT) return;
    int d = deg[i];
    dinv[i] = (d > 0) ? rsqrtf((float)d) : 0.0f;
}

// ---------------- segment offsets via wave-atomic allocation ----------------
__global__ __launch_bounds__(256) void offs_kernel(const int* __restrict__ deg,
                                                   int* __restrict__ offs,
                                                   int* __restrict__ counter) {
    int i = blockIdx.x * 256 + threadIdx.x;
    int lane = threadIdx.x & 63;
    int v = (i < 2 * N_ENT) ? deg[i] : 0;
    int pre = v;
    #pragma unroll
    for (int d = 1; d < 64; d <<= 1) {
        int t = __shfl_up(pre, d);
        if (lane >= d) pre += t;
    }
    int total = __shfl(pre, 63);
    int base = 0;
    if (lane == 0) base = atomicAdd(counter, total);
    base = __shfl(base, 0);
    if (i < 2 * N_ENT) offs[i] = base + pre - v;
}

// ---------------- fill CSR records {col|t<<17, norm} ----------------
__global__ __launch_bounds__(256) void fill_kernel(const int* __restrict__ rows,
                                                   const int* __restrict__ cols,
                                                   const int* __restrict__ et,
                                                   const float* __restrict__ dinv,
                                                   const int* __restrict__ offs,
                                                   int* __restrict__ cursor,
                                                   uint2* __restrict__ recs) {
    int e = blockIdx.x * 256 + threadIdx.x;
    if (e >= NUM_EDGES) return;
    int half = (e >= E_HALF) ? 1 : 0;
    int g = half * N_ENT + rows[e];
    int col = cols[e];
    int t = et[e];
    int pos = atomicAdd(&cursor[g], 1);
    float norm = dinv[g] * dinv[half * N_ENT + col];
    recs[offs[g] + pos] = make_uint2((unsigned)col | ((unsigned)t << 17),
                                     __float_as_uint(norm));
}

// ---------------- prep: xl = bf16(x - loop_rel) ----------------
__global__ __launch_bounds__(256) void prep_x_kernel(const float4* __restrict__ x4,
                                                     const float4* __restrict__ loop4,
                                                     ushort4* __restrict__ xl4) {
    int i = blockIdx.x * 256 + threadIdx.x;
    if (i >= N_ENT * 32) return;
    float4 v = x4[i];
    float4 lr = loop4[i & 31];
    ushort4 o;
    o.x = f2bf(v.x - lr.x);
    o.y = f2bf(v.y - lr.y);
    o.z = f2bf(v.z - lr.z);
    o.w = f2bf(v.w - lr.w);
    xl4[i] = o;
}

// ---------------- prep: wt[n][384] = bf16 W^T concat ; rp = bf16(r - loop_rel) ----------------
__global__ __launch_bounds__(256) void prep_wr_kernel(const float* __restrict__ w_in,
                                                      const float* __restrict__ w_out,
                                                      const float* __restrict__ w_loop,
                                                      const float* __restrict__ r,
                                                      const float* __restrict__ loop_rel,
                                                      unsigned short* __restrict__ wt,
                                                      unsigned short* __restrict__ rp) {
    int i = blockIdx.x * 256 + threadIdx.x;
    if (i < 128 * 384) {
        int n = i / 384;
        int k = i % 384;
        int s = k >> 7;
        int kk = k & 127;
        const float* W = (s == 0) ? w_in : (s == 1) ? w_out : w_loop;
        wt[i] = f2bf(W[kk * DIM + n]);
    } else {
        int j = i - 128 * 384;
        if (j < NUM_REL * DIM)
            rp[j] = f2bf(r[j] - loop_rel[j & 127]);
    }
}

// ---------------- gather-aggregate: 16 lanes per (row,half), 2-edge unroll ----------------
#define ACC8(X, V, NRM)                                        \
    acc[0] += (NRM) * (bf_lo((X).x) - bf_lo((V).x));           \
    acc[1] += (NRM) * (bf_hi((X).x) - bf_hi((V).x));           \
    acc[2] += (NRM) * (bf_lo((X).y) - bf_lo((V).y));           \
    acc[3] += (NRM) * (bf_hi((X).y) - bf_hi((V).y));           \
    acc[4] += (NRM) * (bf_lo((X).z) - bf_lo((V).z));           \
    acc[5] += (NRM) * (bf_hi((X).z) - bf_hi((V).z));           \
    acc[6] += (NRM) * (bf_lo((X).w) - bf_lo((V).w));           \
    acc[7] += (NRM) * (bf_hi((X).w) - bf_hi((V).w));

__global__ __launch_bounds__(256) void gather_agg_kernel(const int* __restrict__ offs,
                                                         const int* __restrict__ deg,
                                                         const uint2* __restrict__ recs,
                                                         const unsigned short* __restrict__ xl,
                                                         const unsigned short* __restrict__ rp,
                                                         unsigned short* __restrict__ agg) {
    int gid = blockIdx.x * 256 + threadIdx.x;
    int g = gid >> 4;
    if (g >= 2 * N_ENT) return;
    int c = gid & 15;                    // lane covers 16 B = 8 bf16
    int e = offs[g];
    int end = e + deg[g];
    float acc[8] = {0.f, 0.f, 0.f, 0.f, 0.f, 0.f, 0.f, 0.f};
    for (; e + 2 <= end; e += 2) {
        uint2 rA = recs[e];
        uint2 rB = recs[e + 1];
        uint4 xA = ((const uint4*)(xl + (size_t)(rA.x & 0x1ffff) * DIM))[c];
        uint4 vA = ((const uint4*)(rp + (size_t)(rA.x >> 17) * DIM))[c];
        uint4 xB = ((const uint4*)(xl + (size_t)(rB.x & 0x1ffff) * DIM))[c];
        uint4 vB = ((const uint4*)(rp + (size_t)(rB.x >> 17) * DIM))[c];
        float nA = __uint_as_float(rA.y);
        float nB = __uint_as_float(rB.y);
        ACC8(xA, vA, nA)
        ACC8(xB, vB, nB)
    }
    if (e < end) {
        uint2 rA = recs[e];
        uint4 xA = ((const uint4*)(xl + (size_t)(rA.x & 0x1ffff) * DIM))[c];
        uint4 vA = ((const uint4*)(rp + (size_t)(rA.x >> 17) * DIM))[c];
        float nA = __uint_as_float(rA.y);
        ACC8(xA, vA, nA)
    }
    uint4 o;
    o.x = pack2bf(acc[0], acc[1]);
    o.y = pack2bf(acc[2], acc[3]);
    o.z = pack2bf(acc[4], acc[5]);
    o.w = pack2bf(acc[6], acc[7]);
    ((uint4*)(agg + (size_t)g * DIM))[c] = o;
}

// ---------------- MFMA GEMM, LDS-staged (m97 structure + T2 source-side swizzle) ----------------
// out = tanh(([aggA|aggB|xl] @ Wcat)/3 + bias). M=100000, N=128, K=384.
// 128 rows/block, 4 waves 2x2 (64x64 each), BK=64, 6 K-steps, 2 barriers/step.
__global__ __launch_bounds__(256) void mfma_gemm_kernel(const unsigned short* __restrict__ aggA,
                                                        const unsigned short* __restrict__ aggB,
                                                        const unsigned short* __restrict__ xl,
                                                        const unsigned short* __restrict__ wt,
                                                        const float* __restrict__ bias,
                                                        float* __restrict__ out) {
    __shared__ char smem[32768];
    char* Alds = smem;              // [128 rows][128 B]  (64 bf16/row, source-swizzled)
    char* Blds = smem + 16384;      // [128 n   ][128 B]

    int tid = threadIdx.x;
    int wave = tid >> 6;
    int lane = tid & 63;
    int wm = wave >> 1, wn = wave & 1;
    int row0 = blockIdx.x * 128;
    int lr = lane & 15;
    int lkb = (lane >> 4) * 16;          // frag k byte offset within 64B mfma slice

    // staging decomposition: 64 lanes = 8 rows x 8 chunks of 16B
    int sr  = lane >> 3;                               // 0..7 row within chunk
    int ssb = ((lane & 7) << 4) ^ (sr << 4);           // swizzled source byte in 128B slice

    const unsigned short* Asrc[3] = {aggA, aggB, xl};

    f32x4 acc[4][4];
    #pragma unroll
    for (int mi = 0; mi < 4; ++mi)
        #pragma unroll
        for (int ni = 0; ni < 4; ++ni)
            acc[mi][ni] = (f32x4){0.f, 0.f, 0.f, 0.f};

    for (int step = 0; step < 6; ++step) {
        int s = step >> 1;
        int k0b = (step & 1) * 128;                    // byte offset within 256B source row
        const char* Ab = (const char*)Asrc[s];
        const char* Bb = (const char*)wt + s * 256 + k0b;   // wt row stride 768B

        if (step) __syncthreads();                     // previous tile fully consumed
        #pragma unroll
        for (int j = 0; j < 4; ++j) {
            int rl = wave * 32 + j * 8;                // uniform per instruction
            int grow = row0 + rl + sr;
            if (grow > N_ENT - 1) grow = N_ENT - 1;
            gll16(Ab + (size_t)grow * 256 + k0b + ssb, Alds + rl * 128);
        }
        #pragma unroll
        for (int j = 0; j < 4; ++j) {
            int nl = wave * 32 + j * 8;
            gll16(Bb + (size_t)(nl + sr) * 768 + ssb, Blds + nl * 128);
        }
        __syncthreads();                               // vmcnt(0) drain + barrier

        #pragma unroll
        for (int kk = 0; kk < 2; ++kk) {
            int kb = kk * 64 + lkb;                    // 16B-aligned byte in [0,128)
            short8 a[4], b[4];
            #pragma unroll
            for (int mi = 0; mi < 4; ++mi) {
                int ar = wm * 64 + mi * 16 + lr;
                a[mi] = *(const short8*)(Alds + ar * 128 + (kb ^ ((ar & 7) << 4)));
            }
            #pragma unroll
            for (int ni = 0; ni < 4; ++ni) {
                int bn = wn * 64 + ni * 16 + lr;
                b[ni] = *(const short8*)(Blds + bn * 128 + (kb ^ ((bn & 7) << 4)));
            }
            #pragma unroll
            for (int mi = 0; mi < 4; ++mi)
                #pragma unroll
                for (int ni = 0; ni < 4; ++ni)
                    acc[mi][ni] = __builtin_amdgcn_mfma_f32_16x16x32_bf16(a[mi], b[ni], acc[mi][ni], 0, 0, 0);
        }
    }

    int col0 = wn * 64;
    int row0w = row0 + wm * 64;
    const float third = 1.0f / 3.0f;
    float bb[4];
    #pragma unroll
    for (int ni = 0; ni < 4; ++ni) bb[ni] = bias[col0 + ni * 16 + lr];

    #pragma unroll
    for (int mi = 0; mi < 4; ++mi) {
        #pragma unroll
        for (int reg = 0; reg < 4; ++reg) {
            int grow = row0w + mi * 16 + (lane >> 4) * 4 + reg;
            if (grow < N_ENT) {
                #pragma unroll
                for (int ni = 0; ni < 4; ++ni)
                    out[(size_t)grow * DIM + col0 + ni * 16 + lr] =
                        tanhf(acc[mi][ni][reg] * third + bb[ni]);
            }
        }
    }
}

// ---------------- r_out = r @ w_rel  (400x128 @ 128x128, f32) ----------------
__global__ __launch_bounds__(128) void rel_gemm_kernel(const float* __restrict__ r,
                                                       const float* __restrict__ w_rel,
                                                       float* __restrict__ r_out) {
    __shared__ float rrow[128];
    int i = blockIdx.x;
    int j = threadIdx.x;
    rrow[j] = r[i * DIM + j];
    __syncthreads();
    float acc = 0.0f;
    #pragma unroll 8
    for (int k = 0; k < DIM; ++k)
        acc += rrow[k] * w_rel[k * DIM + j];
    r_out[i * DIM + j] = acc;
}

extern "C" void kernel_launch(void* const* d_in, const int* in_sizes, int n_in,
                              void* d_out, int out_size, void* d_ws, size_t ws_size,
                              hipStream_t stream) {
    const float* x        = (const float*)d_in[0];
    const float* r        = (const float*)d_in[1];
    const int*   ei       = (const int*)d_in[2];   // [2][800000]: rows then cols
    const int*   et       = (const int*)d_in[3];
    const float* w_in     = (const float*)d_in[4];
    const float* w_out    = (const float*)d_in[5];
    const float* w_loop   = (const float*)d_in[6];
    const float* w_rel    = (const float*)d_in[7];
    const float* loop_rel = (const float*)d_in[8];
    const float* bias     = (const float*)d_in[9];

    float* out   = (float*)d_out;            // 100000*128
    float* r_out = out + (size_t)N_ENT * DIM;

    // -------- workspace layout --------
    unsigned short* agg = (unsigned short*)d_ws;            // [2N][128] bf16 (in | out)
    unsigned short* xl  = agg + 2ull * N_ENT * DIM;         // [N][128] bf16
    unsigned short* wt  = xl + (size_t)N_ENT * DIM;         // [128][384] bf16
    unsigned short* rp  = wt + 128 * 384;                   // [400][128] bf16
    uint2* recs = (uint2*)(rp + NUM_REL * DIM);             // 800k x 8 B
    int*   deg     = (int*)(recs + NUM_EDGES);              // 2N
    int*   cursor  = deg + 2 * N_ENT;                       // 2N
    int*   counter = cursor + 2 * N_ENT;                    // 1 (+3 pad)
    int*   offs    = counter + 4;                           // 2N
    float* dinv    = (float*)(offs + 2 * N_ENT);            // 2N

    const int* rows = ei;
    const int* cols = ei + NUM_EDGES;

    hipMemsetAsync(deg, 0, (4ull * N_ENT + 4) * sizeof(int), stream);

    deg_kernel<<<(NUM_EDGES + 255) / 256, 256, 0, stream>>>(rows, deg);
    dinv_kernel<<<(2 * N_ENT + 255) / 256, 256, 0, stream>>>(deg, dinv);
    offs_kernel<<<(2 * N_ENT + 255) / 256, 256, 0, stream>>>(deg, offs, counter);
    fill_kernel<<<(NUM_EDGES + 255) / 256, 256, 0, stream>>>(rows, cols, et, dinv, offs, cursor, recs);

    prep_x_kernel<<<(N_ENT * 32 + 255) / 256, 256, 0, stream>>>(
        (const float4*)x, (const float4*)loop_rel, (ushort4*)xl);
    prep_wr_kernel<<<(128 * 384 + NUM_REL * DIM + 255) / 256, 256, 0, stream>>>(
        w_in, w_out, w_loop, r, loop_rel, wt, rp);

    gather_agg_kernel<<<(2 * N_ENT * 16 + 255) / 256, 256, 0, stream>>>(
        offs, deg, recs, xl, rp, agg);

    mfma_gemm_kernel<<<(N_ENT + 127) / 128, 256, 0, stream>>>(
        agg, agg + (size_t)N_ENT * DIM, xl, wt, bias, out);

    rel_gemm_kernel<<<NUM_REL, 128, 0, stream>>>(r, w_rel, r_out);
}